// Round 10
// baseline (148.897 us; speedup 1.0000x reference)
//
#include <hip/hip_runtime.h>

#define NGRAPHS 256
#define CHUNK 4096     // edges per count/scatter block (391 blocks @ E=1.6M, 512 thr)
#define BINR 256       // nodes per dst-range bin (bin = dst >> 8)
#define CAPB 6144      // bucket capacity per bin (mean ~4092 -> huge slack)
#define MAXB 512       // max bins (N <= 131072)
#define NMAX 2048      // max nodes/graph in k4 LDS (actual ~470)

// ---- k1: fused, 512 threads. Blocks [0,NBLKE): per-chunk histogram of dst>>8
//      -> C (int4 reads). Blocks [NBLKE,...): float4 dots (32 rows/block)
//      + graph boundaries. ----
__global__ __launch_bounds__(512) void k1_fused(
    const float* __restrict__ x,
    const int*   __restrict__ batch,
    const int*   __restrict__ ei,        // [2,E]: src then dst
    const float* __restrict__ w_rel,
    const float* __restrict__ w_root,
    float* __restrict__ p, float* __restrict__ r,
    int* __restrict__ starts, int* __restrict__ ends,
    int* __restrict__ C,
    int N, int E, int NBLKE, int NBINS, int vecE)
{
    __shared__ int hist[MAXB];
    int tid = threadIdx.x;

    if ((int)blockIdx.x < NBLKE) {       // ---- edge-count role ----
        for (int b = tid; b < NBINS; b += 512) hist[b] = 0;
        __syncthreads();
        int beg = blockIdx.x * CHUNK;
        int end = min(beg + CHUNK, E);
        if (vecE) {
            const int4* d4 = (const int4*)(ei + E);
            for (int i = (beg >> 2) + tid; i < (end >> 2); i += 512) {
                int4 d = d4[i];
                atomicAdd(&hist[d.x >> 8], 1);
                atomicAdd(&hist[d.y >> 8], 1);
                atomicAdd(&hist[d.z >> 8], 1);
                atomicAdd(&hist[d.w >> 8], 1);
            }
        } else {
            for (int i = beg + tid; i < end; i += 512)
                atomicAdd(&hist[ei[E + i] >> 8], 1);
        }
        __syncthreads();
        for (int b = tid; b < NBINS; b += 512)
            C[(size_t)blockIdx.x * NBINS + b] = hist[b];
        return;
    }

    // ---- node-dot role: 32 rows/block, 16 lanes/row, float4/lane ----
    int row = ((int)blockIdx.x - NBLKE) * 32 + (tid >> 4);
    int fq  = tid & 15;
    if (row >= N) return;
    if (fq == 0) {                       // graph boundaries (handles empty graphs)
        int b = batch[row];
        if (row == 0) {
            for (int g = 0; g < b; ++g) { starts[g] = 0; ends[g] = 0; }
            starts[b] = 0;
        } else {
            int bp = batch[row - 1];
            if (bp != b) {
                ends[bp] = row;
                for (int g = bp + 1; g < b; ++g) { starts[g] = row; ends[g] = row; }
                starts[b] = row;
            }
        }
        if (row == N - 1) {
            ends[b] = N;
            for (int g = b + 1; g < NGRAPHS; ++g) { starts[g] = N; ends[g] = N; }
        }
    }
    float4 v  = *(const float4*)(x + (size_t)row * 64 + fq * 4);
    float4 wr = ((const float4*)w_rel)[fq];
    float4 wo = ((const float4*)w_root)[fq];
    float a = v.x * wr.x + v.y * wr.y + v.z * wr.z + v.w * wr.w;
    float c = v.x * wo.x + v.y * wo.y + v.z * wo.z + v.w * wo.w;
    a += __shfl_down(a, 8); c += __shfl_down(c, 8);   // reduce within 16-lane group
    a += __shfl_down(a, 4); c += __shfl_down(c, 4);
    a += __shfl_down(a, 2); c += __shfl_down(c, 2);
    a += __shfl_down(a, 1); c += __shfl_down(c, 1);
    if (fq == 0) { p[row] = a; r[row] = c; }
}

// ---- kA2: per-bin column scan of C (NBLK <= 512) -> absolute exclusive
//      bases + per-bin totals. Single-level 512-thread Hillis-Steele. ----
__global__ __launch_bounds__(512) void kA2_scan(
    int* __restrict__ C, int* __restrict__ cursor, int NBLK, int NBINS)
{
    __shared__ int sh[512];
    int b = blockIdx.x;
    int t = threadIdx.x;
    int c = (t < NBLK) ? C[(size_t)t * NBINS + b] : 0;
    sh[t] = c;
    __syncthreads();
    #pragma unroll
    for (int off = 1; off < 512; off <<= 1) {
        int v = (t >= off) ? sh[t - off] : 0;
        __syncthreads();
        sh[t] += v;
        __syncthreads();
    }
    if (t < NBLK) C[(size_t)t * NBINS + b] = b * CAPB + (sh[t] - c);
    if (t == 511) cursor[b] = sh[t];
}

// ---- kA3: scatter payload v=p[src] (float) + local dst (uchar) into
//      dst-range buckets. 512 threads, int4 edge reads, LDS bump cursors,
//      no global atomics. ----
__global__ __launch_bounds__(512) void kA3_scatter(
    const int* __restrict__ ei,
    const float* __restrict__ p,
    const int* __restrict__ C,
    float* __restrict__ bucket_v,
    unsigned char* __restrict__ bucket_d,
    int E, int NBINS, int vecE)
{
    __shared__ int cur[MAXB];
    int tid = threadIdx.x;
    for (int b = tid; b < NBINS; b += 512)
        cur[b] = C[(size_t)blockIdx.x * NBINS + b];
    __syncthreads();
    int beg = blockIdx.x * CHUNK;
    int end = min(beg + CHUNK, E);
    if (vecE) {
        const int4* s4 = (const int4*)ei;
        const int4* d4 = (const int4*)(ei + E);
        for (int i = (beg >> 2) + tid; i < (end >> 2); i += 512) {
            int4 d = d4[i];
            int4 s = s4[i];
            float v0 = p[s.x], v1 = p[s.y], v2 = p[s.z], v3 = p[s.w];
            int b0 = d.x >> 8, p0 = atomicAdd(&cur[b0], 1);
            if (p0 < (b0 + 1) * CAPB) { bucket_v[p0] = v0; bucket_d[p0] = (unsigned char)(d.x & 255); }
            int b1 = d.y >> 8, p1 = atomicAdd(&cur[b1], 1);
            if (p1 < (b1 + 1) * CAPB) { bucket_v[p1] = v1; bucket_d[p1] = (unsigned char)(d.y & 255); }
            int b2 = d.z >> 8, p2 = atomicAdd(&cur[b2], 1);
            if (p2 < (b2 + 1) * CAPB) { bucket_v[p2] = v2; bucket_d[p2] = (unsigned char)(d.z & 255); }
            int b3 = d.w >> 8, p3 = atomicAdd(&cur[b3], 1);
            if (p3 < (b3 + 1) * CAPB) { bucket_v[p3] = v3; bucket_d[p3] = (unsigned char)(d.w & 255); }
        }
    } else {
        for (int i = beg + tid; i < end; i += 512) {
            int d = ei[E + i];
            int s = ei[i];
            float v = p[s];
            int b = d >> 8;
            int pos = atomicAdd(&cur[b], 1);
            if (pos < (b + 1) * CAPB) {
                bucket_v[pos] = v;
                bucket_d[pos] = (unsigned char)(d & 255);
            }
        }
    }
}

// ---- fallback (ws too small): zero + device-scope atomic scatter + score ----
__global__ __launch_bounds__(256) void kZ_zero(float* __restrict__ a, int N)
{
    int i = blockIdx.x * 256 + threadIdx.x;
    if (i < N) a[i] = 0.0f;
}
__global__ __launch_bounds__(256) void k2_scatter(
    const int* __restrict__ ei, const float* __restrict__ p,
    float* aggdot, int E)
{
    int i = blockIdx.x * 256 + threadIdx.x;
    if (i < E) unsafeAtomicAdd(&aggdot[ei[E + i]], p[ei[i]]);
}
__global__ __launch_bounds__(256) void kS_score(
    const float* __restrict__ aggdot, const float* __restrict__ r,
    const float* __restrict__ brel, float* __restrict__ score, int N)
{
    int i = blockIdx.x * 256 + threadIdx.x;
    if (i < N) score[i] = tanhf(aggdot[i] + brel[0] + r[i]);
}

// ---- k4: fused per-graph bucket reduce (overlapping bins, range-filtered)
//      + tanh + stable top-k rank (float4 LDS j-loop) + compacted pool.
//      bucket_v == nullptr -> fallback mode: read precomputed score. ----
__global__ __launch_bounds__(512) void k4_pool(
    const float* __restrict__ x,
    const float* __restrict__ r,
    const float* __restrict__ brel,
    const int* __restrict__ starts,
    const int* __restrict__ ends,
    const int* __restrict__ cursor,
    const float* __restrict__ bucket_v,
    const unsigned char* __restrict__ bucket_d,
    const float* __restrict__ score,
    float* __restrict__ out)
{
    __shared__ __align__(16) float sc[NMAX];
    __shared__ int   kidx[NMAX / 2 + 64];
    __shared__ float kw[NMAX / 2 + 64];
    __shared__ float accs[8][64][4];
    __shared__ int   pctr;

    int g   = blockIdx.x;
    int tid = threadIdx.x;
    int start = starts[g];
    int n     = ends[g] - start;
    if (n > NMAX) n = NMAX;              // safety clamp (never hit)
    int k = (n + 1) >> 1;                // ceil(0.5*n); kept count == k exactly
    if (tid == 0) pctr = 0;

    if (bucket_v) {
        for (int i = tid; i < n; i += 512) sc[i] = 0.0f;
        __syncthreads();
        if (n > 0) {
            int b0 = start >> 8;
            int b1 = (start + n - 1) >> 8;
            for (int b = b0; b <= b1; ++b) {
                int lo   = b * CAPB;
                int cnt  = min(cursor[b], CAPB);
                int base = b * BINR - start;       // idx = base + local_dst
                const float4* v4 = (const float4*)(bucket_v + lo);
                const uchar4* d4 = (const uchar4*)(bucket_d + lo);
                int quart = cnt >> 2;
                for (int e = tid; e < quart; e += 512) {
                    uchar4 dd = d4[e];
                    float4 vv = v4[e];
                    int i0 = base + dd.x;
                    int i1 = base + dd.y;
                    int i2 = base + dd.z;
                    int i3 = base + dd.w;
                    if ((unsigned)i0 < (unsigned)n) atomicAdd(&sc[i0], vv.x);  // ds_add_f32
                    if ((unsigned)i1 < (unsigned)n) atomicAdd(&sc[i1], vv.y);
                    if ((unsigned)i2 < (unsigned)n) atomicAdd(&sc[i2], vv.z);
                    if ((unsigned)i3 < (unsigned)n) atomicAdd(&sc[i3], vv.w);
                }
                int tail = cnt & 3;
                if (tid < tail) {
                    int e  = (quart << 2) + tid;
                    int i0 = base + bucket_d[lo + e];
                    if ((unsigned)i0 < (unsigned)n) atomicAdd(&sc[i0], bucket_v[lo + e]);
                }
            }
        }
        __syncthreads();
        float bias = brel[0];
        for (int i = tid; i < n; i += 512)
            sc[i] = tanhf(sc[i] + bias + r[start + i]);
    } else {
        for (int i = tid; i < n; i += 512) sc[i] = score[start + i];
    }
    __syncthreads();

    // stable rank (lexsort tie-break: score desc, index asc) + compaction.
    // j-loop vectorized: ds_read_b128 (12 cyc/4 elems vs 4x5.8 scalar).
    int n4 = n & ~3;
    for (int i = tid; i < n; i += 512) {
        float si = sc[i];
        int rank = 0;
        int j = 0;
        for (; j < n4; j += 4) {
            float4 s4 = *(const float4*)&sc[j];
            rank += (s4.x > si) || (s4.x == si && (j + 0) < i);
            rank += (s4.y > si) || (s4.y == si && (j + 1) < i);
            rank += (s4.z > si) || (s4.z == si && (j + 2) < i);
            rank += (s4.w > si) || (s4.w == si && (j + 3) < i);
        }
        for (; j < n; ++j) {
            float sj = sc[j];
            rank += (sj > si) || (sj == si && j < i);
        }
        if (rank < k) {
            int pos = atomicAdd(&pctr, 1);
            kidx[pos] = i;
            kw[pos]   = si;
        }
    }
    __syncthreads();
    int k32 = (k + 31) & ~31;
    for (int e = k + tid; e < k32; e += 512) { kidx[e] = 0; kw[e] = 0.0f; }
    __syncthreads();

    // weighted pool over compacted kept list: wave wg rows {wg*4+32t+rgrp},
    // lane = rgrp*16+fq -> each 16-lane group reads one contiguous 256B row.
    int wg   = tid >> 6;
    int lane = tid & 63;
    int rgrp = lane >> 4;
    int fq   = lane & 15;
    float a0 = 0.0f, a1 = 0.0f, a2 = 0.0f, a3 = 0.0f;
    #pragma unroll 2
    for (int e = wg * 4 + rgrp; e < k32; e += 32) {
        float wv = kw[e];
        int row  = start + kidx[e];
        const float4 v = *(const float4*)(x + (size_t)row * 64 + fq * 4);
        a0 += v.x * wv; a1 += v.y * wv; a2 += v.z * wv; a3 += v.w * wv;
    }
    accs[wg][lane][0] = a0; accs[wg][lane][1] = a1;
    accs[wg][lane][2] = a2; accs[wg][lane][3] = a3;
    __syncthreads();
    if (tid < 64) {
        int f = tid;
        float sum = 0.0f;
        #pragma unroll
        for (int gg = 0; gg < 8; ++gg)
            #pragma unroll
            for (int rg = 0; rg < 4; ++rg)
                sum += accs[gg][rg * 16 + (f >> 2)][f & 3];
        out[(size_t)g * 64 + f] = sum / fmaxf((float)k, 1.0f);
    }
}

extern "C" void kernel_launch(void* const* d_in, const int* in_sizes, int n_in,
                              void* d_out, int out_size, void* d_ws, size_t ws_size,
                              hipStream_t stream) {
    const float* x      = (const float*)d_in[0];
    const int*   ei     = (const int*)  d_in[1];
    const int*   batch  = (const int*)  d_in[2];
    const float* w_rel  = (const float*)d_in[3];
    const float* b_rel  = (const float*)d_in[4];
    const float* w_root = (const float*)d_in[5];
    float* out = (float*)d_out;

    int N = in_sizes[2];
    int E = in_sizes[1] / 2;
    int NBLKE = (E + CHUNK - 1) / CHUNK;
    int NBINS = (N + BINR - 1) / BINR;
    int vecE  = ((E & 3) == 0);

    // ws layout (4B units unless noted): p[N], r[N], score[N] (fallback),
    // starts[256], ends[256], cursor[MAXB], C[NBLKE*NBINS],
    // bucket_v float[NBINS*CAPB], bucket_d uchar[NBINS*CAPB]
    float* p      = (float*)d_ws;
    float* r      = p + (size_t)N;
    float* score  = r + (size_t)N;
    int*   starts = (int*)(score + (size_t)N);
    int*   ends   = starts + NGRAPHS;
    int*   cursor = ends + NGRAPHS;
    int*   C      = cursor + MAXB;
    float* bucket_v = (float*)(C + (size_t)NBLKE * NBINS);
    unsigned char* bucket_d = (unsigned char*)(bucket_v + (size_t)NBINS * CAPB);
    size_t need = ((size_t)3 * N + 2 * NGRAPHS + MAXB
                   + (size_t)NBLKE * NBINS + (size_t)NBINS * CAPB) * 4
                  + (size_t)NBINS * CAPB;

    bool binned = (need <= ws_size) && (NBLKE <= 512) && (NBINS <= MAXB)
                  && (N < (1 << 24));

    int dotblks = (N + 31) / 32;
    if (binned) {
        k1_fused<<<NBLKE + dotblks, 512, 0, stream>>>(x, batch, ei, w_rel, w_root,
                                                      p, r, starts, ends, C,
                                                      N, E, NBLKE, NBINS, vecE);
        kA2_scan<<<NBINS, 512, 0, stream>>>(C, cursor, NBLKE, NBINS);
        kA3_scatter<<<NBLKE, 512, 0, stream>>>(ei, p, C, bucket_v, bucket_d,
                                               E, NBINS, vecE);
        k4_pool<<<NGRAPHS, 512, 0, stream>>>(x, r, b_rel, starts, ends, cursor,
                                             bucket_v, bucket_d, nullptr, out);
    } else {
        float* aggdot = (float*)C;   // fallback-only alias
        k1_fused<<<dotblks, 512, 0, stream>>>(x, batch, ei, w_rel, w_root,
                                              p, r, starts, ends, C, N, E, 0,
                                              NBINS, vecE);
        kZ_zero<<<(N + 255) / 256, 256, 0, stream>>>(aggdot, N);
        k2_scatter<<<(E + 255) / 256, 256, 0, stream>>>(ei, p, aggdot, E);
        kS_score<<<(N + 255) / 256, 256, 0, stream>>>(aggdot, r, b_rel, score, N);
        k4_pool<<<NGRAPHS, 512, 0, stream>>>(x, r, b_rel, starts, ends, cursor,
                                             nullptr, nullptr, score, out);
    }
}

// Round 11
// 134.193 us; speedup vs baseline: 1.1096x; 1.1096x over previous
//
#include <hip/hip_runtime.h>

#define NGRAPHS 256
#define CHUNK 4096     // edges per count/scatter block (391 blocks @ E=1.6M, 512 thr)
#define BINR 256       // nodes per dst-range bin (bin = dst >> 8)
#define CAPB 6144      // bucket capacity per bin (mean ~4092 -> huge slack)
#define MAXB 512       // max bins (N <= 131072)
#define NMAX 2048      // max nodes/graph in k4 LDS (actual ~470)

// ---- k1: fused, 512 threads. Blocks [0,NBLKE): per-chunk histogram of dst>>8
//      -> C (int4 reads). Blocks [NBLKE,...): float4 dots (32 rows/block)
//      + graph boundaries. ----
__global__ __launch_bounds__(512) void k1_fused(
    const float* __restrict__ x,
    const int*   __restrict__ batch,
    const int*   __restrict__ ei,        // [2,E]: src then dst
    const float* __restrict__ w_rel,
    const float* __restrict__ w_root,
    float* __restrict__ p, float* __restrict__ r,
    int* __restrict__ starts, int* __restrict__ ends,
    int* __restrict__ C,
    int N, int E, int NBLKE, int NBINS, int vecE)
{
    __shared__ int hist[MAXB];
    int tid = threadIdx.x;

    if ((int)blockIdx.x < NBLKE) {       // ---- edge-count role ----
        for (int b = tid; b < NBINS; b += 512) hist[b] = 0;
        __syncthreads();
        int beg = blockIdx.x * CHUNK;
        int end = min(beg + CHUNK, E);
        if (vecE) {
            const int4* d4 = (const int4*)(ei + E);
            for (int i = (beg >> 2) + tid; i < (end >> 2); i += 512) {
                int4 d = d4[i];
                atomicAdd(&hist[d.x >> 8], 1);
                atomicAdd(&hist[d.y >> 8], 1);
                atomicAdd(&hist[d.z >> 8], 1);
                atomicAdd(&hist[d.w >> 8], 1);
            }
        } else {
            for (int i = beg + tid; i < end; i += 512)
                atomicAdd(&hist[ei[E + i] >> 8], 1);
        }
        __syncthreads();
        for (int b = tid; b < NBINS; b += 512)
            C[(size_t)blockIdx.x * NBINS + b] = hist[b];
        return;
    }

    // ---- node-dot role: 32 rows/block, 16 lanes/row, float4/lane ----
    int row = ((int)blockIdx.x - NBLKE) * 32 + (tid >> 4);
    int fq  = tid & 15;
    if (row >= N) return;
    if (fq == 0) {                       // graph boundaries (handles empty graphs)
        int b = batch[row];
        if (row == 0) {
            for (int g = 0; g < b; ++g) { starts[g] = 0; ends[g] = 0; }
            starts[b] = 0;
        } else {
            int bp = batch[row - 1];
            if (bp != b) {
                ends[bp] = row;
                for (int g = bp + 1; g < b; ++g) { starts[g] = row; ends[g] = row; }
                starts[b] = row;
            }
        }
        if (row == N - 1) {
            ends[b] = N;
            for (int g = b + 1; g < NGRAPHS; ++g) { starts[g] = N; ends[g] = N; }
        }
    }
    float4 v  = *(const float4*)(x + (size_t)row * 64 + fq * 4);
    float4 wr = ((const float4*)w_rel)[fq];
    float4 wo = ((const float4*)w_root)[fq];
    float a = v.x * wr.x + v.y * wr.y + v.z * wr.z + v.w * wr.w;
    float c = v.x * wo.x + v.y * wo.y + v.z * wo.z + v.w * wo.w;
    a += __shfl_down(a, 8); c += __shfl_down(c, 8);   // reduce within 16-lane group
    a += __shfl_down(a, 4); c += __shfl_down(c, 4);
    a += __shfl_down(a, 2); c += __shfl_down(c, 2);
    a += __shfl_down(a, 1); c += __shfl_down(c, 1);
    if (fq == 0) { p[row] = a; r[row] = c; }
}

// ---- kA2: per-bin column scan of C (NBLK <= 512) -> absolute exclusive
//      bases + totals. Single-level 512-thread Hillis-Steele. ----
__global__ __launch_bounds__(512) void kA2_scan(
    int* __restrict__ C, int* __restrict__ cursor, int NBLK, int NBINS)
{
    __shared__ int sh[512];
    int b = blockIdx.x;
    int t = threadIdx.x;
    int c = (t < NBLK) ? C[(size_t)t * NBINS + b] : 0;
    sh[t] = c;
    __syncthreads();
    #pragma unroll
    for (int off = 1; off < 512; off <<= 1) {
        int v = (t >= off) ? sh[t - off] : 0;
        __syncthreads();
        sh[t] += v;
        __syncthreads();
    }
    if (t < NBLK) C[(size_t)t * NBINS + b] = b * CAPB + (sh[t] - c);
    if (t == 511) cursor[b] = sh[t];
}

// ---- kA3: scatter packed (src<<8 | dst&255) u32 into dst-range buckets ----
// 512 threads, int4 edge reads; LDS bump cursors; no global atomics.
// Per-(block,bin) writes are sequential runs (~10 entries @ CHUNK=4096).
__global__ __launch_bounds__(512) void kA3_scatter(
    const int* __restrict__ ei,
    const int* __restrict__ C,
    unsigned* __restrict__ bucket,
    int E, int NBINS, int vecE)
{
    __shared__ int cur[MAXB];
    int tid = threadIdx.x;
    for (int b = tid; b < NBINS; b += 512)
        cur[b] = C[(size_t)blockIdx.x * NBINS + b];
    __syncthreads();
    int beg = blockIdx.x * CHUNK;
    int end = min(beg + CHUNK, E);
    if (vecE) {
        const int4* s4 = (const int4*)ei;
        const int4* d4 = (const int4*)(ei + E);
        for (int i = (beg >> 2) + tid; i < (end >> 2); i += 512) {
            int4 d = d4[i];
            int4 s = s4[i];
            int b0 = d.x >> 8, p0 = atomicAdd(&cur[b0], 1);
            if (p0 < (b0 + 1) * CAPB) bucket[p0] = ((unsigned)s.x << 8) | (unsigned)(d.x & 255);
            int b1 = d.y >> 8, p1 = atomicAdd(&cur[b1], 1);
            if (p1 < (b1 + 1) * CAPB) bucket[p1] = ((unsigned)s.y << 8) | (unsigned)(d.y & 255);
            int b2 = d.z >> 8, p2 = atomicAdd(&cur[b2], 1);
            if (p2 < (b2 + 1) * CAPB) bucket[p2] = ((unsigned)s.z << 8) | (unsigned)(d.z & 255);
            int b3 = d.w >> 8, p3 = atomicAdd(&cur[b3], 1);
            if (p3 < (b3 + 1) * CAPB) bucket[p3] = ((unsigned)s.w << 8) | (unsigned)(d.w & 255);
        }
    } else {
        for (int i = beg + tid; i < end; i += 512) {
            int d = ei[E + i];
            int s = ei[i];
            int b = d >> 8;
            int pos = atomicAdd(&cur[b], 1);
            if (pos < (b + 1) * CAPB)
                bucket[pos] = ((unsigned)s << 8) | (unsigned)(d & 255);
        }
    }
}

// ---- kB: one block per bin. uint4 bucket stream (4 entries/load), p gather
//      (L2), LDS float atomics, fused tanh -> final per-node score. ----
__global__ __launch_bounds__(512) void kB_score(
    const unsigned* __restrict__ bucket,
    const int* __restrict__ cursor,
    const float* __restrict__ p,
    const float* __restrict__ r,
    const float* __restrict__ brel,
    float* __restrict__ score, int N)
{
    __shared__ float acc[BINR];
    int tid = threadIdx.x;
    int b   = blockIdx.x;
    if (tid < BINR) acc[tid] = 0.0f;
    __syncthreads();
    int lo  = b * CAPB;
    int cnt = min(cursor[b], CAPB);
    const uint4* bk4 = (const uint4*)(bucket + lo);   // CAPB % 4 == 0 -> aligned
    int quart = cnt >> 2;
    for (int e = tid; e < quart; e += 512) {
        uint4 u = bk4[e];
        float v0 = p[u.x >> 8], v1 = p[u.y >> 8];
        float v2 = p[u.z >> 8], v3 = p[u.w >> 8];
        atomicAdd(&acc[u.x & 255u], v0);              // ds_add_f32
        atomicAdd(&acc[u.y & 255u], v1);
        atomicAdd(&acc[u.z & 255u], v2);
        atomicAdd(&acc[u.w & 255u], v3);
    }
    int tail = cnt & 3;
    if (tid < tail) {
        unsigned u = bucket[lo + (quart << 2) + tid];
        atomicAdd(&acc[u & 255u], p[u >> 8]);
    }
    __syncthreads();
    int node = b * BINR + tid;
    if (tid < BINR && node < N)
        score[node] = tanhf(acc[tid] + brel[0] + r[node]);
}

// ---- fallback (ws too small): zero + device-scope atomic scatter + score ----
__global__ __launch_bounds__(256) void kZ_zero(float* __restrict__ a, int N)
{
    int i = blockIdx.x * 256 + threadIdx.x;
    if (i < N) a[i] = 0.0f;
}
__global__ __launch_bounds__(256) void k2_scatter(
    const int* __restrict__ ei, const float* __restrict__ p,
    float* aggdot, int E)
{
    int i = blockIdx.x * 256 + threadIdx.x;
    if (i < E) unsafeAtomicAdd(&aggdot[ei[E + i]], p[ei[i]]);
}
__global__ __launch_bounds__(256) void kS_score(
    const float* __restrict__ aggdot, const float* __restrict__ r,
    const float* __restrict__ brel, float* __restrict__ score, int N)
{
    int i = blockIdx.x * 256 + threadIdx.x;
    if (i < N) score[i] = tanhf(aggdot[i] + brel[0] + r[i]);
}

// ---- k4: per-graph stable top-k rank (float4 LDS j-loop) + compacted
//      float4 weighted pool ----
__global__ __launch_bounds__(512) void k4_pool(
    const float* __restrict__ x,
    const float* __restrict__ score,
    const int* __restrict__ starts,
    const int* __restrict__ ends,
    float* __restrict__ out)
{
    __shared__ __align__(16) float sc[NMAX];
    __shared__ int   kidx[NMAX / 2 + 64];
    __shared__ float kw[NMAX / 2 + 64];
    __shared__ float accs[8][64][4];
    __shared__ int   pctr;

    int g   = blockIdx.x;
    int tid = threadIdx.x;
    int start = starts[g];
    int n     = ends[g] - start;
    if (n > NMAX) n = NMAX;              // safety clamp (never hit)
    int k = (n + 1) >> 1;                // ceil(0.5*n); kept count == k exactly
    if (tid == 0) pctr = 0;

    for (int i = tid; i < n; i += 512) sc[i] = score[start + i];
    __syncthreads();

    // stable rank (lexsort tie-break: score desc, index asc) + compaction.
    // j-loop vectorized: ds_read_b128 (12 cyc/4 elems vs 4x5.8 scalar).
    int n4 = n & ~3;
    for (int i = tid; i < n; i += 512) {
        float si = sc[i];
        int rank = 0;
        int j = 0;
        for (; j < n4; j += 4) {
            float4 s4 = *(const float4*)&sc[j];
            rank += (s4.x > si) || (s4.x == si && (j + 0) < i);
            rank += (s4.y > si) || (s4.y == si && (j + 1) < i);
            rank += (s4.z > si) || (s4.z == si && (j + 2) < i);
            rank += (s4.w > si) || (s4.w == si && (j + 3) < i);
        }
        for (; j < n; ++j) {
            float sj = sc[j];
            rank += (sj > si) || (sj == si && j < i);
        }
        if (rank < k) {
            int pos = atomicAdd(&pctr, 1);
            kidx[pos] = i;
            kw[pos]   = si;
        }
    }
    __syncthreads();
    int k32 = (k + 31) & ~31;
    for (int e = k + tid; e < k32; e += 512) { kidx[e] = 0; kw[e] = 0.0f; }
    __syncthreads();

    // weighted pool over compacted kept list: wave wg rows {wg*4+32t+rgrp},
    // lane = rgrp*16+fq -> each 16-lane group reads one contiguous 256B row.
    int wg   = tid >> 6;
    int lane = tid & 63;
    int rgrp = lane >> 4;
    int fq   = lane & 15;
    float a0 = 0.0f, a1 = 0.0f, a2 = 0.0f, a3 = 0.0f;
    #pragma unroll 2
    for (int e = wg * 4 + rgrp; e < k32; e += 32) {
        float wv = kw[e];
        int row  = start + kidx[e];
        const float4 v = *(const float4*)(x + (size_t)row * 64 + fq * 4);
        a0 += v.x * wv; a1 += v.y * wv; a2 += v.z * wv; a3 += v.w * wv;
    }
    accs[wg][lane][0] = a0; accs[wg][lane][1] = a1;
    accs[wg][lane][2] = a2; accs[wg][lane][3] = a3;
    __syncthreads();
    if (tid < 64) {
        int f = tid;
        float sum = 0.0f;
        #pragma unroll
        for (int gg = 0; gg < 8; ++gg)
            #pragma unroll
            for (int rg = 0; rg < 4; ++rg)
                sum += accs[gg][rg * 16 + (f >> 2)][f & 3];
        out[(size_t)g * 64 + f] = sum / fmaxf((float)k, 1.0f);
    }
}

extern "C" void kernel_launch(void* const* d_in, const int* in_sizes, int n_in,
                              void* d_out, int out_size, void* d_ws, size_t ws_size,
                              hipStream_t stream) {
    const float* x      = (const float*)d_in[0];
    const int*   ei     = (const int*)  d_in[1];
    const int*   batch  = (const int*)  d_in[2];
    const float* w_rel  = (const float*)d_in[3];
    const float* b_rel  = (const float*)d_in[4];
    const float* w_root = (const float*)d_in[5];
    float* out = (float*)d_out;

    int N = in_sizes[2];
    int E = in_sizes[1] / 2;
    int NBLKE = (E + CHUNK - 1) / CHUNK;
    int NBINS = (N + BINR - 1) / BINR;
    int vecE  = ((E & 3) == 0);

    // ws layout (4B units): p[N], r[N], score[N], starts[256], ends[256],
    // cursor[MAXB], C[NBLKE*NBINS], bucket u32[NBINS*CAPB]
    float* p      = (float*)d_ws;
    float* r      = p + (size_t)N;
    float* score  = r + (size_t)N;
    int*   starts = (int*)(score + (size_t)N);
    int*   ends   = starts + NGRAPHS;
    int*   cursor = ends + NGRAPHS;
    int*   C      = cursor + MAXB;
    unsigned* bucket = (unsigned*)(C + (size_t)NBLKE * NBINS);
    size_t need = ((size_t)3 * N + 2 * NGRAPHS + MAXB
                   + (size_t)NBLKE * NBINS + (size_t)NBINS * CAPB) * 4;

    bool binned = (need <= ws_size) && (NBLKE <= 512) && (NBINS <= MAXB)
                  && (N < (1 << 24));

    int dotblks = (N + 31) / 32;
    if (binned) {
        k1_fused<<<NBLKE + dotblks, 512, 0, stream>>>(x, batch, ei, w_rel, w_root,
                                                      p, r, starts, ends, C,
                                                      N, E, NBLKE, NBINS, vecE);
        kA2_scan<<<NBINS, 512, 0, stream>>>(C, cursor, NBLKE, NBINS);
        kA3_scatter<<<NBLKE, 512, 0, stream>>>(ei, C, bucket, E, NBINS, vecE);
        kB_score<<<NBINS, 512, 0, stream>>>(bucket, cursor, p, r, b_rel, score, N);
    } else {
        float* aggdot = (float*)C;   // fallback-only alias
        k1_fused<<<dotblks, 512, 0, stream>>>(x, batch, ei, w_rel, w_root,
                                              p, r, starts, ends, C, N, E, 0,
                                              NBINS, vecE);
        kZ_zero<<<(N + 255) / 256, 256, 0, stream>>>(aggdot, N);
        k2_scatter<<<(E + 255) / 256, 256, 0, stream>>>(ei, p, aggdot, E);
        kS_score<<<(N + 255) / 256, 256, 0, stream>>>(aggdot, r, b_rel, score, N);
    }
    k4_pool<<<NGRAPHS, 512, 0, stream>>>(x, score, starts, ends, out);
}